// Round 8
// baseline (199.755 us; speedup 1.0000x reference)
//
#include <hip/hip_runtime.h>
#include <hip/hip_bf16.h>

#define DM 1024
#define HID 64
#define NSTEP 6
#define RSTEP (1.0f/6.0f)

using short8  = __attribute__((ext_vector_type(8))) short;
using short4v = __attribute__((ext_vector_type(4))) short;
using f32x4   = __attribute__((ext_vector_type(4))) float;

// workspace byte offsets
#define WS_W1P 0          // 1024x64 bf16 packed A-frags (131072 B)
#define WS_W2P 131072     // 64x1024 bf16 packed A-frags (131072 B)
#define WS_GP  262144     // 64x64 bf16 packed A-frags (8192 B)
#define WS_U   270336     // 64 f32  (u = b2 @ W1k)

// LDS byte offsets (total 26112 B -> 2 blocks/CU, wave-limited)
#define L_H0 0            // H ping  [32][72] bf16, pitch 144 (4608)
#define L_H1 4608         // H pong
#define L_HB 9216         // Hb = (h/6)*Hsum
#define L_B2 13824        // b2 staged f32[1024] (4096)
#define L_GP 17920        // G packed frags staged (8192)
#define LDS_TOTAL 26112
#define HP 144

// LDS-only barrier: order LDS ops, do NOT drain vmcnt — global weight
// loads issued before the barrier stay in flight and land inside P6.
#define BAR() asm volatile("s_waitcnt lgkmcnt(0)\n\ts_barrier" ::: "memory")

__device__ __forceinline__ short f2bf(float f) {   // RNE via HW cvt
    __hip_bfloat16 h = __float2bfloat16(f);
    short s;
    __builtin_memcpy(&s, &h, 2);
    return s;
}
__device__ __forceinline__ float ftanh(float x) {
    x = fminf(fmaxf(x, -10.f), 10.f);
    float e = __expf(2.f * x);
    return __fdividef(e - 1.f, e + 1.f);
}

// ---------------- prep: pack weights to MFMA fragment layout ----------------
// A-frag layout for mfma_f32_16x16x32_bf16: lane l holds M-row (l&15),
// k = (l>>4)*8 + i (8 consecutive k). Packed so each lane loads one short8.
__global__ void k_prep(const float* __restrict__ W1, const float* __restrict__ W2,
                       const float* __restrict__ b2,
                       short* __restrict__ W1P, short* __restrict__ W2P,
                       short* __restrict__ GP, float* __restrict__ U) {
    __shared__ float red[4][64];
    int b = blockIdx.x;
    int t = threadIdx.x;           // 256 threads
    int l = t & 63, q4 = t >> 6;
    if (b < 128) {                 // W1k (1024x64) -> W1P[kk<32][c<4][l][8]
        if (t < 64) {
            int kk = b >> 2, c = b & 3;
            int col = c * 16 + (l & 15);
            int kb = kk * 32 + ((l >> 4) << 3);
            short8 v;
            #pragma unroll
            for (int i = 0; i < 8; ++i) v[i] = f2bf(W1[(kb + i) * HID + col]);
            *(short8*)(W1P + (((kk * 4 + c) * 64) + l) * 8) = v;
        }
    } else if (b < 256) {          // W2 (64x1024) -> W2P[kk2<2][ct<64][l][8]
        if (t < 64) {
            int bb = b - 128;
            int kk2 = bb >> 6, ct = bb & 63;
            int col = ct * 16 + (l & 15);
            int kb = kk2 * 32 + ((l >> 4) << 3);
            short8 v;
            #pragma unroll
            for (int i = 0; i < 8; ++i) v[i] = f2bf(W2[(kb + i) * DM + col]);
            *(short8*)(W2P + (((kk2 * 64 + ct) * 64) + l) * 8) = v;
        }
    } else if (b < 320) {          // G[j][i] = sum_d W2[j][d]*W1[d][i]; j = b-256
        int j = b - 256;
        float acc = 0.f;
        #pragma unroll 8
        for (int d = q4 * 256; d < q4 * 256 + 256; ++d)
            acc += W2[j * DM + d] * W1[d * HID + l];
        red[q4][l] = acc;
        __syncthreads();
        if (t < 64) {
            float a = red[0][l] + red[1][l] + red[2][l] + red[3][l];
            int kk = j >> 5, lk = (j >> 3) & 3, ii = j & 7, c = l >> 4, lo = l & 15;
            GP[(((kk * 4 + c) * 64) + lk * 16 + lo) * 8 + ii] = f2bf(a);
        }
    } else {                       // u[i] = sum_d b2[d]*W1[d][i]
        float acc = 0.f;
        #pragma unroll 8
        for (int d = q4 * 256; d < q4 * 256 + 256; ++d)
            acc += b2[d] * W1[d * HID + l];
        red[q4][l] = acc;
        __syncthreads();
        if (t < 64) U[l] = red[0][l] + red[1][l] + red[2][l] + red[3][l];
    }
}

// ---------------- fused RK4 neural-ODE kernel ----------------
// Block: 512 thr (8 waves), 32 rows. Incremental sz (R7 algebra):
//   sz' = sz + Hb@G + h*u ; GEMM1 runs once in the prologue.
// STAGE tiling (H compute): wave (rw=w>>2, cw=w&3): rows rw*16+l15,
//   hid cols cw*16+hq*4. 4 lgkmcnt-only barriers/step.
// P6 tiling (z update): UNIQUE-COLUMN split — wave w owns cols
//   [w*128, w*128+128) for ALL 32 rows: lane l holds rows {l15, l15+16}
//   (row-group g per MFMA), z[2][8] f32x4 = 64 VGPRs, static indexing.
//   Each W2P fragment is read by exactly ONE wave per block -> per-CU
//   weight L2 traffic halves vs R7 (was 4 blocks x full panel).
// G frags + b2 staged in LDS (register relief). MFMA: A = packed weights
// (M = out-col), B = z/H rows; D: m=(lane>>4)*4+reg (col), n=lane&15 (row).
// launch_bounds(512) + waves_per_eu(4,4): pin 4 waves/EU -> hard 128-VGPR
// cap with allocator targeting exactly that (R2/R4 spill lessons).
__global__ __launch_bounds__(512) __attribute__((amdgpu_waves_per_eu(4, 4)))
void k_ode(
        const float* __restrict__ X, const float* __restrict__ W1,
        const float* __restrict__ b1, const float* __restrict__ b2,
        const short* __restrict__ W1P, const short* __restrict__ W2P,
        const short* __restrict__ GP, const float* __restrict__ U,
        float* __restrict__ OUT) {
    extern __shared__ char smem[];
    const int t = threadIdx.x;
    const int lane = t & 63;
    const int w = t >> 6;                    // 0..7
    const int rw = w >> 2, cw = w & 3;       // stage tiling
    const int hq = lane >> 4;
    const int l15 = lane & 15;
    const int hcol0 = cw * 16 + hq * 4;      // hid-col base (stage epilogues)
    const int srow = rw * 16 + l15;          // stage row
    const size_t row0 = (size_t)blockIdx.x * 32;

    // stage b2 + G into LDS (first use is after stage1's barrier)
    if (t < 256) *(f32x4*)(smem + L_B2 + t * 16) = *(const f32x4*)(b2 + t * 4);
    *(f32x4*)(smem + L_GP + t * 16) = *(const f32x4*)((const float*)GP + t * 4);

    // per-lane persistent constants
    f32x4 u4   = *(const f32x4*)(U + hcol0);
    f32x4 b14  = *(const f32x4*)(b1 + hcol0);
    f32x4 w1t4 = *(const f32x4*)(W1 + DM * HID + hcol0);   // time row of W1

    // ---- z master: lane owns rows {l15, l15+16}, cols w*128+qc*16+hq*4 ----
    f32x4 z[2][8];
    #pragma unroll
    for (int g = 0; g < 2; ++g) {
        const float* zr = X + (row0 + g * 16 + l15) * DM + w * 128;
        #pragma unroll
        for (int qc = 0; qc < 8; ++qc)
            z[g][qc] = *(const f32x4*)(zr + qc * 16 + hq * 4);
    }

    // ---- prologue GEMM1 (once): sz = x @ W1k for stage tile ----
    f32x4 sz;
    {
        const float* xrow = X + (row0 + srow) * DM;
        const short8* wp = (const short8*)W1P + (cw * 64 + lane);
        f32x4 a0 = (f32x4){0.f, 0.f, 0.f, 0.f};
        f32x4 a1 = (f32x4){0.f, 0.f, 0.f, 0.f};
        #pragma unroll 4
        for (int kk = 0; kk < 32; kk += 2) {
            const float* xp = xrow + (kk << 5) + (hq << 3);
            f32x4 lo0 = *(const f32x4*)(xp);
            f32x4 hi0 = *(const f32x4*)(xp + 4);
            f32x4 lo1 = *(const f32x4*)(xp + 32);
            f32x4 hi1 = *(const f32x4*)(xp + 36);
            short8 zf0, zf1;
            #pragma unroll
            for (int j = 0; j < 4; ++j) {
                zf0[j] = f2bf(lo0[j]); zf0[4 + j] = f2bf(hi0[j]);
                zf1[j] = f2bf(lo1[j]); zf1[4 + j] = f2bf(hi1[j]);
            }
            a0 = __builtin_amdgcn_mfma_f32_16x16x32_bf16(wp[kk * 256],       zf0, a0, 0, 0, 0);
            a1 = __builtin_amdgcn_mfma_f32_16x16x32_bf16(wp[(kk + 1) * 256], zf1, a1, 0, 0, 0);
        }
        sz = a0 + a1;
    }

    for (int s = 0; s < NSTEP; ++s) {
        const float tcur = RSTEP * (float)s;

        // stage 1: H1 = tanh(sz + t*w1t + b1)  -> H0
        f32x4 hsum;
        {
            short4v hc;
            #pragma unroll
            for (int j = 0; j < 4; ++j) {
                float T = sz[j] + tcur * w1t4[j] + b14[j];
                float h = ftanh(T);
                hsum[j] = h;
                hc[j] = f2bf(h);
            }
            *(short4v*)(smem + L_H0 + srow * HP + hcol0 * 2) = hc;
        }
        BAR();

        // stages 2..4 via tiny H@G GEMM (G frags from LDS)
        #pragma unroll
        for (int st = 0; st < 3; ++st) {
            const float c_i = (st == 2) ? RSTEP : (0.5f * RSTEP);
            const float t_i = tcur + ((st == 2) ? RSTEP : (0.5f * RSTEP));
            const float w_i = (st == 2) ? 1.f : 2.f;
            const int rbuf = (st & 1) ? L_H1 : L_H0;
            const int wbuf = (st & 1) ? L_H0 : L_H1;

            short8 hf0 = *(const short8*)(smem + rbuf + srow * HP + (hq << 4));
            short8 hf1 = *(const short8*)(smem + rbuf + srow * HP + 64 + (hq << 4));
            short8 gf0 = *(const short8*)(smem + L_GP + (cw * 64 + lane) * 16);
            short8 gf1 = *(const short8*)(smem + L_GP + ((4 + cw) * 64 + lane) * 16);
            f32x4 dd = (f32x4){0.f, 0.f, 0.f, 0.f};
            dd = __builtin_amdgcn_mfma_f32_16x16x32_bf16(gf0, hf0, dd, 0, 0, 0);
            dd = __builtin_amdgcn_mfma_f32_16x16x32_bf16(gf1, hf1, dd, 0, 0, 0);
            short4v hc;
            #pragma unroll
            for (int j = 0; j < 4; ++j) {
                float T = sz[j] + c_i * (dd[j] + u4[j]) + t_i * w1t4[j] + b14[j];
                float h = ftanh(T);
                hsum[j] += w_i * h;
                hc[j] = f2bf(h);
            }
            if (st < 2) {
                *(short4v*)(smem + wbuf + srow * HP + hcol0 * 2) = hc;
            } else {   // Hb = (h/6) * Hsum, GEMM2 B-operand
                short4v hb4;
                #pragma unroll
                for (int j = 0; j < 4; ++j) hb4[j] = f2bf(hsum[j] * (RSTEP / 6.f));
                *(short4v*)(smem + L_HB + srow * HP + hcol0 * 2) = hb4;
            }
            BAR();
        }

        // P6 (barrier-free, unique cols): z += Hb @ W2 + h*b2 for ALL 32
        // rows of cols [w*128,+128); then sz += Hb @ G + h*u.
        {
            const short8* w2p8 = (const short8*)W2P;
            if (s < NSTEP - 1) {
                #pragma unroll
                for (int qc = 0; qc < 8; ++qc) {
                    int ct = w * 8 + qc;
                    short8 wa = w2p8[ct * 64 + lane];
                    short8 wb = w2p8[(64 + ct) * 64 + lane];
                    f32x4 b2v = *(const f32x4*)(smem + L_B2 + ct * 64 + (hq << 4));
                    #pragma unroll
                    for (int g = 0; g < 2; ++g) {
                        short8 hb0 = *(const short8*)(smem + L_HB + (g * 16 + l15) * HP + (hq << 4));
                        short8 hb1 = *(const short8*)(smem + L_HB + (g * 16 + l15) * HP + 64 + (hq << 4));
                        f32x4 p = (f32x4){0.f, 0.f, 0.f, 0.f};
                        p = __builtin_amdgcn_mfma_f32_16x16x32_bf16(wa, hb0, p, 0, 0, 0);
                        p = __builtin_amdgcn_mfma_f32_16x16x32_bf16(wb, hb1, p, 0, 0, 0);
                        #pragma unroll
                        for (int j = 0; j < 4; ++j)
                            z[g][qc][j] += p[j] + RSTEP * b2v[j];
                    }
                }
                // incremental sz update (stage tile rows rw*16)
                short8 hbs0 = *(const short8*)(smem + L_HB + srow * HP + (hq << 4));
                short8 hbs1 = *(const short8*)(smem + L_HB + srow * HP + 64 + (hq << 4));
                short8 gf0 = *(const short8*)(smem + L_GP + (cw * 64 + lane) * 16);
                short8 gf1 = *(const short8*)(smem + L_GP + ((4 + cw) * 64 + lane) * 16);
                f32x4 d = (f32x4){0.f, 0.f, 0.f, 0.f};
                d = __builtin_amdgcn_mfma_f32_16x16x32_bf16(gf0, hbs0, d, 0, 0, 0);
                d = __builtin_amdgcn_mfma_f32_16x16x32_bf16(gf1, hbs1, d, 0, 0, 0);
                #pragma unroll
                for (int j = 0; j < 4; ++j)
                    sz[j] += d[j] + RSTEP * u4[j];
            } else {   // last step: final z straight from regs to OUT (f32)
                #pragma unroll
                for (int qc = 0; qc < 8; ++qc) {
                    int ct = w * 8 + qc;
                    short8 wa = w2p8[ct * 64 + lane];
                    short8 wb = w2p8[(64 + ct) * 64 + lane];
                    f32x4 b2v = *(const f32x4*)(smem + L_B2 + ct * 64 + (hq << 4));
                    #pragma unroll
                    for (int g = 0; g < 2; ++g) {
                        short8 hb0 = *(const short8*)(smem + L_HB + (g * 16 + l15) * HP + (hq << 4));
                        short8 hb1 = *(const short8*)(smem + L_HB + (g * 16 + l15) * HP + 64 + (hq << 4));
                        f32x4 p = (f32x4){0.f, 0.f, 0.f, 0.f};
                        p = __builtin_amdgcn_mfma_f32_16x16x32_bf16(wa, hb0, p, 0, 0, 0);
                        p = __builtin_amdgcn_mfma_f32_16x16x32_bf16(wb, hb1, p, 0, 0, 0);
                        f32x4 nv;
                        #pragma unroll
                        for (int j = 0; j < 4; ++j)
                            nv[j] = z[g][qc][j] + p[j] + RSTEP * b2v[j];
                        *(f32x4*)(OUT + (row0 + g * 16 + l15) * DM + w * 128 + qc * 16 + hq * 4) = nv;
                    }
                }
            }
        }
        // no barrier: next stage1 writes H0 only; every wave already passed
        // the stage-4 barrier (H0's last reader), P6 touches only L_HB/L_B2.
    }
}

extern "C" void kernel_launch(void* const* d_in, const int* in_sizes, int n_in,
                              void* d_out, int out_size, void* d_ws, size_t ws_size,
                              hipStream_t stream) {
    (void)in_sizes; (void)n_in; (void)out_size; (void)ws_size;
    const float* X  = (const float*)d_in[0];
    const float* W1 = (const float*)d_in[1];
    const float* b1 = (const float*)d_in[2];
    const float* W2 = (const float*)d_in[3];
    const float* b2 = (const float*)d_in[4];
    float* OUT = (float*)d_out;
    short* W1P = (short*)((char*)d_ws + WS_W1P);
    short* W2P = (short*)((char*)d_ws + WS_W2P);
    short* GP  = (short*)((char*)d_ws + WS_GP);
    float* U   = (float*)((char*)d_ws + WS_U);

    k_prep<<<321, 256, 0, stream>>>(W1, W2, b2, W1P, W2P, GP, U);
    k_ode<<<512, 512, LDS_TOTAL, stream>>>(X, W1, b1, b2, W1P, W2P, GP, U, OUT);
}

// Round 9
// 114.662 us; speedup vs baseline: 1.7421x; 1.7421x over previous
//
#include <hip/hip_runtime.h>
#include <hip/hip_bf16.h>

#define DM 1024
#define HID 64
#define NSTEP 6
#define RSTEP (1.0f/6.0f)

using short8  = __attribute__((ext_vector_type(8))) short;
using short4v = __attribute__((ext_vector_type(4))) short;
using f32x4   = __attribute__((ext_vector_type(4))) float;

// workspace byte offsets
#define WS_W1P 0          // 1024x64 bf16 packed A-frags (131072 B)
#define WS_W2P 131072     // 64x1024 bf16 packed A-frags (131072 B)
#define WS_GP  262144     // 64x64 bf16 packed A-frags (8192 B)
#define WS_U   270336     // 64 f32  (u = b2 @ W1k)

// LDS byte offsets (total 26112 B)
#define L_H0 0            // H ping  [32][72] bf16, pitch 144 (4608)
#define L_H1 4608         // H pong
#define L_HB 9216         // Hb = (h/6)*Hsum
#define L_B2 13824        // b2 staged f32[1024] (4096)
#define L_GP 17920        // G packed frags staged (8192)
#define LDS_TOTAL 26112
#define HP 144

// LDS-only barrier: order LDS ops, do NOT drain vmcnt — global weight
// loads issued before the barrier stay in flight and land inside P6.
#define BAR() asm volatile("s_waitcnt lgkmcnt(0)\n\ts_barrier" ::: "memory")

__device__ __forceinline__ short f2bf(float f) {   // RNE via HW cvt
    __hip_bfloat16 h = __float2bfloat16(f);
    short s;
    __builtin_memcpy(&s, &h, 2);
    return s;
}
__device__ __forceinline__ float ftanh(float x) {
    x = fminf(fmaxf(x, -10.f), 10.f);
    float e = __expf(2.f * x);
    return __fdividef(e - 1.f, e + 1.f);
}

// ---------------- prep: pack weights to MFMA fragment layout ----------------
// A-frag layout for mfma_f32_16x16x32_bf16: lane l holds M-row (l&15),
// k = (l>>4)*8 + i (8 consecutive k). Packed so each lane loads one short8.
__global__ void k_prep(const float* __restrict__ W1, const float* __restrict__ W2,
                       const float* __restrict__ b2,
                       short* __restrict__ W1P, short* __restrict__ W2P,
                       short* __restrict__ GP, float* __restrict__ U) {
    __shared__ float red[4][64];
    int b = blockIdx.x;
    int t = threadIdx.x;           // 256 threads
    int l = t & 63, q4 = t >> 6;
    if (b < 128) {                 // W1k (1024x64) -> W1P[kk<32][c<4][l][8]
        if (t < 64) {
            int kk = b >> 2, c = b & 3;
            int col = c * 16 + (l & 15);
            int kb = kk * 32 + ((l >> 4) << 3);
            short8 v;
            #pragma unroll
            for (int i = 0; i < 8; ++i) v[i] = f2bf(W1[(kb + i) * HID + col]);
            *(short8*)(W1P + (((kk * 4 + c) * 64) + l) * 8) = v;
        }
    } else if (b < 256) {          // W2 (64x1024) -> W2P[kk2<2][ct<64][l][8]
        if (t < 64) {
            int bb = b - 128;
            int kk2 = bb >> 6, ct = bb & 63;
            int col = ct * 16 + (l & 15);
            int kb = kk2 * 32 + ((l >> 4) << 3);
            short8 v;
            #pragma unroll
            for (int i = 0; i < 8; ++i) v[i] = f2bf(W2[(kb + i) * DM + col]);
            *(short8*)(W2P + (((kk2 * 64 + ct) * 64) + l) * 8) = v;
        }
    } else if (b < 320) {          // G[j][i] = sum_d W2[j][d]*W1[d][i]; j = b-256
        int j = b - 256;
        float acc = 0.f;
        #pragma unroll 8
        for (int d = q4 * 256; d < q4 * 256 + 256; ++d)
            acc += W2[j * DM + d] * W1[d * HID + l];
        red[q4][l] = acc;
        __syncthreads();
        if (t < 64) {
            float a = red[0][l] + red[1][l] + red[2][l] + red[3][l];
            int kk = j >> 5, lk = (j >> 3) & 3, ii = j & 7, c = l >> 4, lo = l & 15;
            GP[(((kk * 4 + c) * 64) + lk * 16 + lo) * 8 + ii] = f2bf(a);
        }
    } else {                       // u[i] = sum_d b2[d]*W1[d][i]
        float acc = 0.f;
        #pragma unroll 8
        for (int d = q4 * 256; d < q4 * 256 + 256; ++d)
            acc += b2[d] * W1[d * HID + l];
        red[q4][l] = acc;
        __syncthreads();
        if (t < 64) U[l] = red[0][l] + red[1][l] + red[2][l] + red[3][l];
    }
}

// ---------------- fused RK4 neural-ODE kernel ----------------
// R8 structure, R3-proven allocation attr. Block: 512 thr (8 waves),
// 32 rows. Incremental sz: sz' = sz + Hb@G + h*u; GEMM1 once in prologue.
// STAGE tiling: wave (rw=w>>2, cw=w&3): rows rw*16+l15, cols cw*16+hq*4.
// P6 tiling (unique cols): wave w owns cols [w*128,+128) for ALL 32 rows;
// lane holds rows {l15, l15+16} -> z[2][8] f32x4 = 64 VGPRs, static idx.
// Each W2P frag read by exactly ONE wave per block (half the per-CU L2
// weight traffic of the 16-row R7 layout).
// ALLOCATION (8-round ledger): ONLY amdgpu_waves_per_eu(2,4) yields
// VGPR=128 without spill (R3/R6/R7); launch_bounds 2nd arg and (4,4)/(2,2)
// /(1,1) all mis-allocate. Live-set here ~120 regs -> fits 128.
__global__ __launch_bounds__(512) __attribute__((amdgpu_waves_per_eu(2, 4)))
void k_ode(
        const float* __restrict__ X, const float* __restrict__ W1,
        const float* __restrict__ b1, const float* __restrict__ b2,
        const short* __restrict__ W1P, const short* __restrict__ W2P,
        const short* __restrict__ GP, const float* __restrict__ U,
        float* __restrict__ OUT) {
    extern __shared__ char smem[];
    const int t = threadIdx.x;
    const int lane = t & 63;
    const int w = t >> 6;                    // 0..7
    const int rw = w >> 2, cw = w & 3;       // stage tiling
    const int hq = lane >> 4;
    const int l15 = lane & 15;
    const int hcol0 = cw * 16 + hq * 4;      // hid-col base (stage epilogues)
    const int srow = rw * 16 + l15;          // stage row
    const size_t row0 = (size_t)blockIdx.x * 32;

    // stage b2 + G into LDS (first use is after stage1's barrier)
    if (t < 256) *(f32x4*)(smem + L_B2 + t * 16) = *(const f32x4*)(b2 + t * 4);
    *(f32x4*)(smem + L_GP + t * 16) = *(const f32x4*)((const float*)GP + t * 4);

    // per-lane persistent constants
    f32x4 u4   = *(const f32x4*)(U + hcol0);
    f32x4 b14  = *(const f32x4*)(b1 + hcol0);
    f32x4 w1t4 = *(const f32x4*)(W1 + DM * HID + hcol0);   // time row of W1

    // ---- z master: lane owns rows {l15, l15+16}, cols w*128+qc*16+hq*4 ----
    f32x4 z[2][8];
    #pragma unroll
    for (int g = 0; g < 2; ++g) {
        const float* zr = X + (row0 + g * 16 + l15) * DM + w * 128;
        #pragma unroll
        for (int qc = 0; qc < 8; ++qc)
            z[g][qc] = *(const f32x4*)(zr + qc * 16 + hq * 4);
    }

    // ---- prologue GEMM1 (once): sz = x @ W1k for stage tile ----
    f32x4 sz;
    {
        const float* xrow = X + (row0 + srow) * DM;
        const short8* wp = (const short8*)W1P + (cw * 64 + lane);
        f32x4 a0 = (f32x4){0.f, 0.f, 0.f, 0.f};
        f32x4 a1 = (f32x4){0.f, 0.f, 0.f, 0.f};
        #pragma unroll 4
        for (int kk = 0; kk < 32; kk += 2) {
            const float* xp = xrow + (kk << 5) + (hq << 3);
            f32x4 lo0 = *(const f32x4*)(xp);
            f32x4 hi0 = *(const f32x4*)(xp + 4);
            f32x4 lo1 = *(const f32x4*)(xp + 32);
            f32x4 hi1 = *(const f32x4*)(xp + 36);
            short8 zf0, zf1;
            #pragma unroll
            for (int j = 0; j < 4; ++j) {
                zf0[j] = f2bf(lo0[j]); zf0[4 + j] = f2bf(hi0[j]);
                zf1[j] = f2bf(lo1[j]); zf1[4 + j] = f2bf(hi1[j]);
            }
            a0 = __builtin_amdgcn_mfma_f32_16x16x32_bf16(wp[kk * 256],       zf0, a0, 0, 0, 0);
            a1 = __builtin_amdgcn_mfma_f32_16x16x32_bf16(wp[(kk + 1) * 256], zf1, a1, 0, 0, 0);
        }
        sz = a0 + a1;
    }

    for (int s = 0; s < NSTEP; ++s) {
        const float tcur = RSTEP * (float)s;

        // stage 1: H1 = tanh(sz + t*w1t + b1)  -> H0
        f32x4 hsum;
        {
            short4v hc;
            #pragma unroll
            for (int j = 0; j < 4; ++j) {
                float T = sz[j] + tcur * w1t4[j] + b14[j];
                float h = ftanh(T);
                hsum[j] = h;
                hc[j] = f2bf(h);
            }
            *(short4v*)(smem + L_H0 + srow * HP + hcol0 * 2) = hc;
        }
        BAR();

        // stages 2..4 via tiny H@G GEMM (G frags from LDS)
        #pragma unroll
        for (int st = 0; st < 3; ++st) {
            const float c_i = (st == 2) ? RSTEP : (0.5f * RSTEP);
            const float t_i = tcur + ((st == 2) ? RSTEP : (0.5f * RSTEP));
            const float w_i = (st == 2) ? 1.f : 2.f;
            const int rbuf = (st & 1) ? L_H1 : L_H0;
            const int wbuf = (st & 1) ? L_H0 : L_H1;

            short8 hf0 = *(const short8*)(smem + rbuf + srow * HP + (hq << 4));
            short8 hf1 = *(const short8*)(smem + rbuf + srow * HP + 64 + (hq << 4));
            short8 gf0 = *(const short8*)(smem + L_GP + (cw * 64 + lane) * 16);
            short8 gf1 = *(const short8*)(smem + L_GP + ((4 + cw) * 64 + lane) * 16);
            f32x4 dd = (f32x4){0.f, 0.f, 0.f, 0.f};
            dd = __builtin_amdgcn_mfma_f32_16x16x32_bf16(gf0, hf0, dd, 0, 0, 0);
            dd = __builtin_amdgcn_mfma_f32_16x16x32_bf16(gf1, hf1, dd, 0, 0, 0);
            short4v hc;
            #pragma unroll
            for (int j = 0; j < 4; ++j) {
                float T = sz[j] + c_i * (dd[j] + u4[j]) + t_i * w1t4[j] + b14[j];
                float h = ftanh(T);
                hsum[j] += w_i * h;
                hc[j] = f2bf(h);
            }
            if (st < 2) {
                *(short4v*)(smem + wbuf + srow * HP + hcol0 * 2) = hc;
            } else {   // Hb = (h/6) * Hsum, GEMM2 B-operand
                short4v hb4;
                #pragma unroll
                for (int j = 0; j < 4; ++j) hb4[j] = f2bf(hsum[j] * (RSTEP / 6.f));
                *(short4v*)(smem + L_HB + srow * HP + hcol0 * 2) = hb4;
            }
            BAR();
        }

        // P6 (barrier-free, unique cols): z += Hb @ W2 + h*b2 for ALL 32
        // rows of cols [w*128,+128); then sz += Hb @ G + h*u.
        // Hb fragments hoisted: 4 ds_reads per step (R8 re-read 32x).
        {
            const short8* w2p8 = (const short8*)W2P;
            short8 hb[2][2];
            #pragma unroll
            for (int g = 0; g < 2; ++g) {
                hb[g][0] = *(const short8*)(smem + L_HB + (g * 16 + l15) * HP + (hq << 4));
                hb[g][1] = *(const short8*)(smem + L_HB + (g * 16 + l15) * HP + 64 + (hq << 4));
            }
            if (s < NSTEP - 1) {
                #pragma unroll
                for (int qc = 0; qc < 8; ++qc) {
                    int ct = w * 8 + qc;
                    short8 wa = w2p8[ct * 64 + lane];
                    short8 wb = w2p8[(64 + ct) * 64 + lane];
                    f32x4 b2v = *(const f32x4*)(smem + L_B2 + ct * 64 + (hq << 4));
                    #pragma unroll
                    for (int g = 0; g < 2; ++g) {
                        f32x4 p = (f32x4){0.f, 0.f, 0.f, 0.f};
                        p = __builtin_amdgcn_mfma_f32_16x16x32_bf16(wa, hb[g][0], p, 0, 0, 0);
                        p = __builtin_amdgcn_mfma_f32_16x16x32_bf16(wb, hb[g][1], p, 0, 0, 0);
                        #pragma unroll
                        for (int j = 0; j < 4; ++j)
                            z[g][qc][j] += p[j] + RSTEP * b2v[j];
                    }
                }
                // incremental sz update (stage tile rows)
                short8 hbs0 = *(const short8*)(smem + L_HB + srow * HP + (hq << 4));
                short8 hbs1 = *(const short8*)(smem + L_HB + srow * HP + 64 + (hq << 4));
                short8 gf0 = *(const short8*)(smem + L_GP + (cw * 64 + lane) * 16);
                short8 gf1 = *(const short8*)(smem + L_GP + ((4 + cw) * 64 + lane) * 16);
                f32x4 d = (f32x4){0.f, 0.f, 0.f, 0.f};
                d = __builtin_amdgcn_mfma_f32_16x16x32_bf16(gf0, hbs0, d, 0, 0, 0);
                d = __builtin_amdgcn_mfma_f32_16x16x32_bf16(gf1, hbs1, d, 0, 0, 0);
                #pragma unroll
                for (int j = 0; j < 4; ++j)
                    sz[j] += d[j] + RSTEP * u4[j];
            } else {   // last step: final z straight from regs to OUT (f32)
                #pragma unroll
                for (int qc = 0; qc < 8; ++qc) {
                    int ct = w * 8 + qc;
                    short8 wa = w2p8[ct * 64 + lane];
                    short8 wb = w2p8[(64 + ct) * 64 + lane];
                    f32x4 b2v = *(const f32x4*)(smem + L_B2 + ct * 64 + (hq << 4));
                    #pragma unroll
                    for (int g = 0; g < 2; ++g) {
                        f32x4 p = (f32x4){0.f, 0.f, 0.f, 0.f};
                        p = __builtin_amdgcn_mfma_f32_16x16x32_bf16(wa, hb[g][0], p, 0, 0, 0);
                        p = __builtin_amdgcn_mfma_f32_16x16x32_bf16(wb, hb[g][1], p, 0, 0, 0);
                        f32x4 nv;
                        #pragma unroll
                        for (int j = 0; j < 4; ++j)
                            nv[j] = z[g][qc][j] + p[j] + RSTEP * b2v[j];
                        *(f32x4*)(OUT + (row0 + g * 16 + l15) * DM + w * 128 + qc * 16 + hq * 4) = nv;
                    }
                }
            }
        }
        // no barrier: next stage1 writes H0 only; every wave already passed
        // the stage-4 barrier (H0's last reader); P6 touches only L_HB/L_B2.
    }
}

extern "C" void kernel_launch(void* const* d_in, const int* in_sizes, int n_in,
                              void* d_out, int out_size, void* d_ws, size_t ws_size,
                              hipStream_t stream) {
    (void)in_sizes; (void)n_in; (void)out_size; (void)ws_size;
    const float* X  = (const float*)d_in[0];
    const float* W1 = (const float*)d_in[1];
    const float* b1 = (const float*)d_in[2];
    const float* W2 = (const float*)d_in[3];
    const float* b2 = (const float*)d_in[4];
    float* OUT = (float*)d_out;
    short* W1P = (short*)((char*)d_ws + WS_W1P);
    short* W2P = (short*)((char*)d_ws + WS_W2P);
    short* GP  = (short*)((char*)d_ws + WS_GP);
    float* U   = (float*)((char*)d_ws + WS_U);

    k_prep<<<321, 256, 0, stream>>>(W1, W2, b2, W1P, W2P, GP, U);
    k_ode<<<512, 512, LDS_TOTAL, stream>>>(X, W1, b1, b2, W1P, W2P, GP, U, OUT);
}